// Round 3
// baseline (1232.102 us; speedup 1.0000x reference)
//
#include <hip/hip_runtime.h>
#include <hip/hip_fp16.h>
#include <math.h>

#define B_ 8
#define P_ 8192
#define N_ 65536
#define K_ 16
#define EPS_ 1e-5f
#define NBK 1024                 // x-buckets per batch
#define BSCALE 20.48f            // NBK / 50.0

// ============================ binning (R5, proven) =========================
__global__ __launch_bounds__(256) void init_bins(int* counts, int* cursors,
                                                 int* xminI, int* xmaxI) {
    int i = blockIdx.x * 256 + threadIdx.x;   // 8192 entries
    counts[i] = 0; cursors[i] = 0;
    xminI[i] = 0x7F7FFFFF;                    // non-neg floats: int order == float order
    xmaxI[i] = 0x80000000;
}

__device__ __forceinline__ int bucket_of(float x) {
    int b = (int)(x * BSCALE);
    return b > (NBK - 1) ? (NBK - 1) : (b < 0 ? 0 : b);
}

__global__ __launch_bounds__(256) void count_kernel(const float* __restrict__ vc,
                                                    int* counts, int* xminI, int* xmaxI) {
    int q = blockIdx.x * 256 + threadIdx.x;
    float4 p = ((const float4*)vc)[q];        // [batch, x, y, z]
    int b = q >> 13;
    int bk = bucket_of(p.y);
    int e = b * NBK + bk;
    atomicAdd(&counts[e], 1);
    int xb = __float_as_int(p.y);
    atomicMin(&xminI[e], xb);
    atomicMax(&xmaxI[e], xb);
}

__global__ __launch_bounds__(1024) void scan_kernel(const int* __restrict__ counts,
                                                    const int* __restrict__ xminI,
                                                    const int* __restrict__ xmaxI,
                                                    int* off, float* xlub, float* xglb) {
    __shared__ int   smi[NBK];
    __shared__ float smf[NBK];
    int b = blockIdx.x, t = threadIdx.x;
    int e = b * NBK + t;

    int c = counts[e];
    smi[t] = c; __syncthreads();
    for (int s = 1; s < NBK; s <<= 1) {
        int u = smi[t]; int v = (t >= s) ? smi[t - s] : 0;
        __syncthreads(); smi[t] = u + v; __syncthreads();
    }
    off[b * (NBK + 1) + t] = smi[t] - c;
    if (t == NBK - 1) off[b * (NBK + 1) + NBK] = smi[t];

    float mx = c ? __int_as_float(xmaxI[e]) : -1e30f;
    smf[t] = mx; __syncthreads();
    for (int s = 1; s < NBK; s <<= 1) {
        float u = smf[t]; float v = (t >= s) ? smf[t - s] : -1e30f;
        __syncthreads(); smf[t] = fmaxf(u, v); __syncthreads();
    }
    xlub[e] = smf[t];
    __syncthreads();

    int r = NBK - 1 - t;
    int cr_ = counts[b * NBK + r];
    float mn = cr_ ? __int_as_float(xminI[b * NBK + r]) : 1e30f;
    smf[t] = mn; __syncthreads();
    for (int s = 1; s < NBK; s <<= 1) {
        float u = smf[t]; float v = (t >= s) ? smf[t - s] : 1e30f;
        __syncthreads(); smf[t] = fminf(u, v); __syncthreads();
    }
    xglb[b * NBK + r] = smf[t];
}

__global__ __launch_bounds__(256) void scatter_kernel(const float* __restrict__ vc,
                                                      const int* __restrict__ off,
                                                      int* cursors, float4* pos4s) {
    int q = blockIdx.x * 256 + threadIdx.x;
    float4 p = ((const float4*)vc)[q];
    int b = q >> 13;
    int bk = bucket_of(p.y);
    int slot = off[b * (NBK + 1) + bk] + atomicAdd(&cursors[b * NBK + bk], 1);
    pos4s[(b << 13) + slot] = make_float4(p.y, p.z, p.w, __int_as_float(q));
}

// ============== knn: single-pass exact top-k, packed f64 keys ==============
// (R2, proven.) NEW in R3: instead of writing raw d2, the epilogue computes
// scal = 2*sigmoid(-sqrt(d2)) ONCE here and stores it as f16 (2 MB instead of
// 4 MB) -- removes sqrt/exp from both edge layers.
__global__ __launch_bounds__(256, 4) void knn3_kernel(const float4* __restrict__ pos4s,
                                                   const float* __restrict__ xlub,
                                                   const float* __restrict__ xglb,
                                                   unsigned short* __restrict__ idx_out,
                                                   __half* __restrict__ scal_out) {
    const int tid   = threadIdx.x;
    const int sub   = tid & 3;                     // position within quad
    const int bb    = blockIdx.x >> 7;             // batch (128 blocks/batch)
    const int bbase = bb << 13;
    const int wq    = blockIdx.x & 127;            // 64-query group within batch
    const int home0 = bbase + ((wq >> 2) << 8);    // aligned 256-tile containing group
    const int qslot = bbase + (wq << 6) + (tid >> 2);
    const float4 me = pos4s[qslot];
    const float qx = me.x, qy = me.y, qz = me.z;
    const int q = __float_as_int(me.w);
    const float* xl = xlub + (bb << 10);
    const float* xg = xglb + (bb << 10);

    __shared__ __align__(16) float4 tile[256];       // 4 KB
    __shared__ int sflags[2];

    const double KINF = __longlong_as_double(0x7F800000LL << 16);  // (inf, idx 0)
    double bd[16];
#pragma unroll
    for (int t = 0; t < 16; ++t) bd[t] = KINF;
    float bd15f = __builtin_huge_valf();             // own 16th distance
    float sbdf  = __builtin_huge_valf();             // quad-union 16th distance

    // 4-stage bitonic cleanup: sorts the bitonic lower-half of a merge.
    auto CLEAN16 = [](double* m) {
#pragma unroll
        for (int dd = 8; dd >= 1; dd >>= 1)
#pragma unroll
            for (int i = 0; i < 16; ++i)
                if ((i & dd) == 0) {
                    double lo = fmin(m[i], m[i | dd]);
                    m[i | dd] = fmax(m[i], m[i | dd]);
                    m[i] = lo;
                }
    };

    // exact union-16th KEY across the quad (all 4 lanes compute same value)
    auto QUAD16K = [&]() -> double {
        double m[16];
#pragma unroll
        for (int i = 0; i < 16; ++i)
            m[i] = fmin(bd[i], __shfl_xor(bd[15 - i], 1, 64));
        CLEAN16(m);
        double t = 0.0;
#pragma unroll
        for (int i = 0; i < 16; ++i)
            t = fmax(t, fmin(m[i], __shfl_xor(m[15 - i], 2, 64)));
        return t;
    };

#define DIST_(c)                                                            \
    float dx = __fsub_rn(qx, (c).x);                                        \
    float dy = __fsub_rn(qy, (c).y);                                        \
    float dz = __fsub_rn(qz, (c).z);                                        \
    float d  = __fadd_rn(__fadd_rn(__fmul_rn(dx,dx), __fmul_rn(dy,dy)),     \
                         __fmul_rn(dz,dz));

#define SCAN_(base, cntT) {                                                 \
    __syncthreads();                                                        \
    if (tid < (cntT)) tile[tid] = pos4s[(base) + tid];                      \
    __syncthreads();                                                        \
    float g_ = fminf(bd15f, sbdf);                                          \
    _Pragma("unroll 4")                                                     \
    for (int j = sub; j < (cntT); j += 4) {                                 \
        float4 c = tile[j];                                                 \
        DIST_(c)                                                            \
        if (d <= g_) {                                                      \
            double key = __longlong_as_double(                              \
                ((long long)((unsigned long long)__float_as_uint(d) << 16)) \
                | (long long)(unsigned long long)((unsigned)__float_as_int(c.w) & 0xFFFFu)); \
            _Pragma("unroll")                                               \
            for (int t = 15; t > 0; --t)                                    \
                bd[t] = fmin(bd[t], fmax(bd[t-1], key));                    \
            bd[0] = fmin(bd[0], key);                                       \
            bd15f = __uint_as_float((unsigned)                              \
                ((unsigned long long)__double_as_longlong(bd[15]) >> 16));  \
            g_ = fminf(bd15f, sbdf);                                        \
        }                                                                   \
    } }

    // ---- home tile, then center-outward expansion (single pass) ----
    SCAN_(home0, 256)
    int sL = home0, sR = home0 + 256;
    for (;;) {
        double sk = QUAD16K();                        // exact union 16th key
        sbdf = __uint_as_float((unsigned)
            ((unsigned long long)__double_as_longlong(sk) >> 16));
        bool needL = false, needR = false;
        if (sL > bbase) {
            float xb = xl[bucket_of(pos4s[sL - 1].x)];   // ub on x of slots < sL
            float t = __fsub_rn(qx, xb);
            needL = __fmul_rn(t, t) <= sbdf;             // tie-inclusive
        }
        if (sR < bbase + P_) {
            float xb = xg[bucket_of(pos4s[sR].x)];       // lb on x of slots >= sR
            float t = __fsub_rn(xb, qx);
            needR = __fmul_rn(t, t) <= sbdf;
        }
        if (tid == 0) { sflags[0] = 0; sflags[1] = 0; }
        __syncthreads();
        if (needL) sflags[0] = 1;
        if (needR) sflags[1] = 1;
        __syncthreads();
        int aL = sflags[0], aR = sflags[1];
        if (!aL && !aR) break;
        if (aL) { int c_ = min(256, sL - bbase);       SCAN_(sL - c_, c_) sL -= c_; }
        if (aR) { int c_ = min(256, bbase + P_ - sR);  SCAN_(sR, c_)      sR += c_; }
    }

    // ---- full sorted union top-16 (all 4 quad lanes converge) ----
    double m[16];
#pragma unroll
    for (int i = 0; i < 16; ++i)
        m[i] = fmin(bd[i], __shfl_xor(bd[15 - i], 1, 64));
    CLEAN16(m);
    double u[16];
#pragma unroll
    for (int i = 0; i < 16; ++i)
        u[i] = fmin(m[i], __shfl_xor(m[15 - i], 2, 64));
    CLEAN16(u);

    // lane sub==0 writes: idx (sorted ascending by (d,idx), exact lax.top_k
    // order) and the f16 precomputed scale.
    if (sub == 0) {
        unsigned long long kk[16];
#pragma unroll
        for (int t = 0; t < 16; ++t)
            kk[t] = (unsigned long long)__double_as_longlong(u[t]);

        ushort4* i4 = (ushort4*)(idx_out + (size_t)q * K_);
        i4[0] = make_ushort4((unsigned short)(kk[0] & 0xFFFFu), (unsigned short)(kk[1] & 0xFFFFu),
                             (unsigned short)(kk[2] & 0xFFFFu), (unsigned short)(kk[3] & 0xFFFFu));
        i4[1] = make_ushort4((unsigned short)(kk[4] & 0xFFFFu), (unsigned short)(kk[5] & 0xFFFFu),
                             (unsigned short)(kk[6] & 0xFFFFu), (unsigned short)(kk[7] & 0xFFFFu));
        i4[2] = make_ushort4((unsigned short)(kk[8] & 0xFFFFu), (unsigned short)(kk[9] & 0xFFFFu),
                             (unsigned short)(kk[10] & 0xFFFFu), (unsigned short)(kk[11] & 0xFFFFu));
        i4[3] = make_ushort4((unsigned short)(kk[12] & 0xFFFFu), (unsigned short)(kk[13] & 0xFFFFu),
                             (unsigned short)(kk[14] & 0xFFFFu), (unsigned short)(kk[15] & 0xFFFFu));

        unsigned pw[8];
#pragma unroll
        for (int i = 0; i < 8; ++i) {
            float d0 = __uint_as_float((unsigned)(kk[2*i]     >> 16));
            float d1 = __uint_as_float((unsigned)(kk[2*i + 1] >> 16));
            float e0 = __expf(-sqrtf(d0));
            float e1 = __expf(-sqrtf(d1));
            float s0 = 2.0f * e0 / (1.0f + e0);
            float s1 = 2.0f * e1 / (1.0f + e1);
            pw[i] = (unsigned)__half_as_ushort(__float2half_rn(s0))
                  | ((unsigned)__half_as_ushort(__float2half_rn(s1)) << 16);
        }
        uint4* s4 = (uint4*)(scal_out + (size_t)q * K_);
        s4[0] = make_uint4(pw[0], pw[1], pw[2], pw[3]);
        s4[1] = make_uint4(pw[4], pw[5], pw[6], pw[7]);
    }
#undef SCAN_
#undef DIST_
}

// ===================== zgemm: per-batch neighbor projection ================
// z[m][o] = sum_c Wr1[o][c] * x1[bcur*8192 + m][c]   (Wr1 = W1[:, 32:64])
// 512 blocks x 256 thr; each quarter-block (64 lanes = all 64 outputs)
// handles 4 points. Output row = 256 B coalesced; table = 2 MB (L2-resident).
__global__ __launch_bounds__(256) void zgemm_kernel(const float* __restrict__ x1,
                                                    const float* __restrict__ W,  // 64 x 64
                                                    float* __restrict__ z, int bcur) {
    const int o  = threadIdx.x & 63;
    const int pg = threadIdx.x >> 6;
    float Wr[32];
    const float4* w4 = (const float4*)(W + o * 64 + 32);
#pragma unroll
    for (int c = 0; c < 8; ++c) {
        float4 v = w4[c];
        Wr[4*c] = v.x; Wr[4*c+1] = v.y; Wr[4*c+2] = v.z; Wr[4*c+3] = v.w;
    }
    const int m0 = blockIdx.x * 16 + pg * 4;
#pragma unroll
    for (int i = 0; i < 4; ++i) {
        const int m = m0 + i;
        const float4* xr = (const float4*)(x1 + (((size_t)bcur << 13) + m) * 32);
        float acc = 0.f;
#pragma unroll
        for (int c = 0; c < 8; ++c) {
            float4 v = xr[c];
            acc = fmaf(Wr[4*c  ], v.x, acc);
            acc = fmaf(Wr[4*c+1], v.y, acc);
            acc = fmaf(Wr[4*c+2], v.z, acc);
            acc = fmaf(Wr[4*c+3], v.w, acc);
        }
        z[m * 64 + o] = acc;
    }
}

// ============================ edgeconv (barrier-free) ======================
// Wave-internal groups (R1/R2, proven). NEW in R3 (USEZ=true, layer 2):
// h = relu(u + z[idx[k]][o]) with u = Ad.xi + b (32 fma once per point) and
// z gathered DIRECTLY from the L2-resident per-batch table (lane o reads
// z[j*64+o] -> 256 B coalesced; no LDS staging, no per-edge GEMM, no Wr
// registers). Phases A and B use the identical u+z path, so BN statistics
// match the data path bit-for-bit. scal is precomputed f16 (from knn).
template<int CIN, int COUT, bool PHA, bool USEZ>
__global__ __launch_bounds__(256) void edge_kernel(
    const float* __restrict__ x,
    const unsigned short* __restrict__ idx,
    const __half* __restrict__ scal,
    const float* __restrict__ W,
    const float* __restrict__ bias,
    const float* __restrict__ wk,
    const float* __restrict__ wq,
    const float* __restrict__ acoef,
    const float* __restrict__ ccoef,
    double* __restrict__ gsum,
    double* __restrict__ gsumsq,
    float* __restrict__ out,
    const float* __restrict__ zbuf,
    int bcur, int niter)
{
    constexpr int LOGC = (COUT == 64) ? 6 : 5;
    constexpr int GPW  = 64 / COUT;
    constexpr int GPB  = 4 * GPW;
    constexpr int C4   = CIN / 4;
    constexpr int SJ   = USEZ ? 4 : ((K_ + 1) * CIN);
    constexpr int HTS  = COUT + 1;
    constexpr int HTN  = PHA ? 1 : (K_ * HTS);
    constexpr int PN   = PHA ? 1 : (K_ * K_);
    constexpr int KQN  = PHA ? 1 : (2 * K_);
    constexpr int SCN  = PHA ? 1 : K_;
    constexpr int WKQN = PHA ? 1 : (2 * COUT);

    const int tid  = threadIdx.x;
    const int wave = tid >> 6;
    const int lane = tid & 63;
    const int lo   = lane & (COUT - 1);
    const int grp  = lane >> LOGC;
    const int gidx = wave * GPW + grp;

    __shared__ __align__(16) float sj_s[GPB][SJ];
    __shared__ __align__(16) float hT_s[GPB][HTN];
    __shared__ __align__(16) float p_s[GPB][PN];
    __shared__ __align__(16) float kqv_s[GPB][KQN];
    __shared__ __align__(16) float rden_s[GPB][SCN];
    __shared__ __align__(16) float scal_s[GPB][SCN];
    __shared__ __align__(16) float wkq_s[WKQN];

    float Ad[CIN];
    float Wr[USEZ ? 1 : CIN];
#pragma unroll
    for (int c = 0; c < CIN; ++c) {
        float wl = W[lo * (2*CIN) + c];
        float wr = W[lo * (2*CIN) + CIN + c];
        Ad[c] = wl - wr;
        if constexpr (!USEZ) Wr[c] = wr;
    }
    const float b_s = bias[lo];

    float a_s = 0.f, c_s = 0.f;
    if constexpr (!PHA) {
        a_s = acoef[lo]; c_s = ccoef[lo];
        if (tid < COUT)            wkq_s[tid] = wk[tid];
        else if (tid < 2*COUT)     wkq_s[tid] = wq[tid - COUT];
        __syncthreads();   // the ONLY block barrier (wkq_s is cross-wave)
    }

    double lsum = 0.0, lsq = 0.0;
    const int g0      = blockIdx.x * GPB + gidx;
    const int gstride = gridDim.x * GPB;

    for (int it = 0; it < niter; ++it) {
        const int n = USEZ ? ((bcur << 13) + blockIdx.x * GPB + gidx)
                           : (g0 + it * gstride);

        float hn[K_];
        float psum = 0.f, psq = 0.f;

        if constexpr (USEZ) {
            // ---- u = b + Ad.x[n] (point's own row, broadcast reads) ----
            float uacc = b_s;
            const float4* xr = (const float4*)(x + (size_t)n * CIN);
#pragma unroll
            for (int c = 0; c < C4; ++c) {
                float4 v = xr[c];
                uacc = fmaf(Ad[4*c  ], v.x, uacc);
                uacc = fmaf(Ad[4*c+1], v.y, uacc);
                uacc = fmaf(Ad[4*c+2], v.z, uacc);
                uacc = fmaf(Ad[4*c+3], v.w, uacc);
            }
            // ---- gather z rows (coalesced 256 B per k, L2-resident) ----
            const uint4* iw = (const uint4*)(idx + (size_t)n * K_);
            const uint4 ia = iw[0], ib = iw[1];
            float zk[K_];
#define GA(k, w, s) { unsigned j = ((w) >> (s)) & 0xFFFFu;                  \
                      zk[k] = zbuf[(((int)(j & (P_-1))) << LOGC) + lo]; }
            GA(0,  ia.x, 0) GA(1,  ia.x, 16) GA(2,  ia.y, 0) GA(3,  ia.y, 16)
            GA(4,  ia.z, 0) GA(5,  ia.z, 16) GA(6,  ia.w, 0) GA(7,  ia.w, 16)
            GA(8,  ib.x, 0) GA(9,  ib.x, 16) GA(10, ib.y, 0) GA(11, ib.y, 16)
            GA(12, ib.z, 0) GA(13, ib.z, 16) GA(14, ib.w, 0) GA(15, ib.w, 16)
#undef GA
#pragma unroll
            for (int k = 0; k < K_; ++k) {
                float h = fmaxf(uacc + zk[k], 0.f);
                if constexpr (PHA) { psum += h; psq = fmaf(h, h, psq); }
                else               hn[k] = fmaf(a_s, h, c_s);
            }
            if constexpr (!PHA) {
                if (lo < K_)
                    scal_s[gidx][lo] = __half2float(scal[(size_t)n * K_ + lo]);
            }
            __builtin_amdgcn_wave_barrier();   // scal_s -> epilogue reads
        } else {
            // ---- stage xj rows (k<K) and xi row (k==K) into LDS (float4) ----
            {
                const float4* xs  = (const float4*)x;
                float4*       sj4 = (float4*)sj_s[gidx];
                constexpr int TOT4 = (K_ + 1) * C4;
#pragma unroll
                for (int e0 = 0; e0 < TOT4; e0 += COUT) {
                    int e = e0 + lo;
                    if (e < TOT4) {
                        int r = e / C4;
                        int c = e - r * C4;
                        int row = (r < K_) ? (int)idx[n * K_ + r] : n;
                        sj4[e] = xs[row * C4 + c];
                    }
                }
            }
            if constexpr (!PHA) {
                if (lo < K_)
                    scal_s[gidx][lo] = __half2float(scal[(size_t)n * K_ + lo]);
            }
            __builtin_amdgcn_wave_barrier();   // staging -> compute (wave-internal)

            const float* sj = sj_s[gidx];
            float t0 = b_s;
#pragma unroll
            for (int c = 0; c < C4; ++c) {
                float4 v = ((const float4*)(sj + K_ * CIN))[c];
                t0 = fmaf(Ad[4*c  ], v.x, t0);
                t0 = fmaf(Ad[4*c+1], v.y, t0);
                t0 = fmaf(Ad[4*c+2], v.z, t0);
                t0 = fmaf(Ad[4*c+3], v.w, t0);
            }
#pragma unroll
            for (int k = 0; k < K_; ++k) {
                float acc = t0;
                const float4* xrr = (const float4*)(sj + k * CIN);
#pragma unroll
                for (int c = 0; c < C4; ++c) {
                    float4 v = xrr[c];
                    acc = fmaf(Wr[4*c  ], v.x, acc);
                    acc = fmaf(Wr[4*c+1], v.y, acc);
                    acc = fmaf(Wr[4*c+2], v.z, acc);
                    acc = fmaf(Wr[4*c+3], v.w, acc);
                }
                float h = fmaxf(acc, 0.f);
                if constexpr (PHA) { psum += h; psq = fmaf(h, h, psq); }
                else               hn[k] = fmaf(a_s, h, c_s);
            }
        }

        if constexpr (PHA) {
            lsum += (double)psum;        // f64 only across points
            lsq  += (double)psq;
        }

        if constexpr (!PHA) {
            // transpose to LDS (padded stride -> conflict-free columns)
            float* hT = hT_s[gidx];
#pragma unroll
            for (int k = 0; k < K_; ++k) hT[k * HTS + lo] = hn[k];
            __builtin_amdgcn_wave_barrier();   // transpose -> Kv/Qv

            const int kk   = lo & 15;
            const int role = lo >> 4;
            float av = 0.f;
            const float* hrow = hT + kk * HTS;
            int obase; const float* wv;
            if constexpr (COUT == 64) { obase = (role & 1) * 32; wv = wkq_s + ((role >> 1) ? COUT : 0); }
            else                      { obase = 0;               wv = wkq_s + (role ? COUT : 0); }
#pragma unroll
            for (int j = 0; j < 32; ++j)
                av = fmaf(hrow[obase + j], wv[obase + j], av);
            if constexpr (COUT == 64) {
                // halves combine in-register: lanes {kk,kk+16}->Kv, {kk+32,kk+48}->Qv
                float sum2 = av + __shfl_xor(av, 16, 64);
                if (lo < 16)                  kqv_s[gidx][kk] = sum2;        // Kv
                else if (lo >= 32 && lo < 48) kqv_s[gidx][16 + kk] = sum2;   // Qv
            } else {
                kqv_s[gidx][lo] = av;   // [0,16)=Kv, [16,32)=Qv
            }
            __builtin_amdgcn_wave_barrier();   // kqv -> softmax

            if (lo < K_) {
                const int qq = lo;
                const float qv = kqv_s[gidx][K_ + qq];
                float mx = -__builtin_huge_valf();
#pragma unroll
                for (int k = 0; k < K_; ++k) mx = fmaxf(mx, kqv_s[gidx][k] * qv);
                float den = 0.f;
#pragma unroll
                for (int k = 0; k < K_; ++k) {
                    float e = __expf(kqv_s[gidx][k] * qv - mx);
                    den += e;
                    p_s[gidx][k * K_ + qq] = e;
                }
                rden_s[gidx][qq] = 1.0f / den;
            }
            __builtin_amdgcn_wave_barrier();   // softmax -> weighted sum

            float hq[K_];
#pragma unroll
            for (int qq = 0; qq < K_; ++qq) hq[qq] = 0.f;
#pragma unroll
            for (int k = 0; k < K_; ++k) {
                const float hnk = hn[k];
                const float4* p4 = (const float4*)(p_s[gidx] + k * K_);
#pragma unroll
                for (int j = 0; j < 4; ++j) {
                    float4 v = p4[j];
                    hq[4*j  ] = fmaf(hnk, v.x, hq[4*j  ]);
                    hq[4*j+1] = fmaf(hnk, v.y, hq[4*j+1]);
                    hq[4*j+2] = fmaf(hnk, v.z, hq[4*j+2]);
                    hq[4*j+3] = fmaf(hnk, v.w, hq[4*j+3]);
                }
            }
            float res = -__builtin_huge_valf();
#pragma unroll
            for (int j = 0; j < 4; ++j) {
                float4 sc = ((const float4*)scal_s[gidx])[j];
                float4 rd = ((const float4*)rden_s[gidx])[j];
                res = fmaxf(res, sc.x * (hq[4*j  ] * rd.x));
                res = fmaxf(res, sc.y * (hq[4*j+1] * rd.y));
                res = fmaxf(res, sc.z * (hq[4*j+2] * rd.z));
                res = fmaxf(res, sc.w * (hq[4*j+3] * rd.w));
            }
            out[(size_t)n * COUT + lo] = res;
            __builtin_amdgcn_wave_barrier();   // epilogue -> next-iter staging
        } else {
            __builtin_amdgcn_wave_barrier();   // compute -> next-iter staging
        }
    }

    if constexpr (PHA) {
        if constexpr (COUT == 32) {
            // fold the two half-wave groups (shuffle across lane 32 boundary)
            long long bs = __double_as_longlong(lsum);
            int l0 = __shfl_xor((int)(bs & 0xffffffffLL), 32, 64);
            int h0 = __shfl_xor((int)(bs >> 32), 32, 64);
            lsum += __longlong_as_double(((long long)h0 << 32) | (unsigned long long)(unsigned int)l0);
            bs = __double_as_longlong(lsq);
            l0 = __shfl_xor((int)(bs & 0xffffffffLL), 32, 64);
            h0 = __shfl_xor((int)(bs >> 32), 32, 64);
            lsq += __longlong_as_double(((long long)h0 << 32) | (unsigned long long)(unsigned int)l0);
        }
        __shared__ double redS[4][COUT];
        __shared__ double redQ[4][COUT];
        if (lane < COUT) { redS[wave][lane] = lsum; redQ[wave][lane] = lsq; }
        __syncthreads();
        if (tid < COUT) {
            double ss = redS[0][tid] + redS[1][tid] + redS[2][tid] + redS[3][tid];
            double qq = redQ[0][tid] + redQ[1][tid] + redQ[2][tid] + redQ[3][tid];
            atomicAdd(&gsum[tid], ss);
            atomicAdd(&gsumsq[tid], qq);
        }
    }
}

__global__ void finalize_kernel(const double* __restrict__ gsum, const double* __restrict__ gsumsq,
                                const float* __restrict__ gamma, const float* __restrict__ beta,
                                float* __restrict__ a, float* __restrict__ c, int cout)
{
    int o = threadIdx.x;
    if (o < cout) {
        const double inv = 1.0 / ((double)N_ * (double)K_);
        double mu  = gsum[o] * inv;
        double var = gsumsq[o] * inv - mu * mu;
        double rs  = 1.0 / sqrt(var + (double)EPS_);
        double av  = rs * (double)gamma[o];
        a[o] = (float)av;
        c[o] = (float)((double)beta[o] - mu * av);
    }
}

__global__ __launch_bounds__(256) void copy_vc(const float4* __restrict__ src,
                                               float4* __restrict__ dst) {
    int i = blockIdx.x * 256 + threadIdx.x;
    dst[i] = src[i];
}

extern "C" void kernel_launch(void* const* d_in, const int* in_sizes, int n_in,
                              void* d_out, int out_size, void* d_ws, size_t ws_size,
                              hipStream_t stream)
{
    const float* pillar = (const float*)d_in[0];
    const float* vc     = (const float*)d_in[1];
    const float* W0  = (const float*)d_in[2];
    const float* b0  = (const float*)d_in[3];
    const float* g0  = (const float*)d_in[4];
    const float* be0 = (const float*)d_in[5];
    const float* wk0 = (const float*)d_in[6];
    const float* wq0 = (const float*)d_in[7];
    const float* W1  = (const float*)d_in[8];
    const float* b1  = (const float*)d_in[9];
    const float* g1  = (const float*)d_in[10];
    const float* be1 = (const float*)d_in[11];
    const float* wk1 = (const float*)d_in[12];
    const float* wq1 = (const float*)d_in[13];

    // ---- workspace map (max used: 15,934,240 B -- same proven bound) ----
    // [0,2M)        idx        (N*K u16)
    // [2M,4M)       scal f16   (N*K)
    // [4M,12M)      x1 f32     (N*32)
    // [12M,14M)     zbuf f32   (8192*64, per-batch neighbor projection)
    // [14,680,064)  dsum 2KB; [14,682,112) coef 1KB
    // [14,688,256)  binning block (pos4s etc., dead after knn)
    char* ws = (char*)d_ws;
    unsigned short* idx = (unsigned short*)ws;
    __half* scal = (__half*)(ws + (size_t)2*1024*1024);
    float*  x1   = (float*)(ws + (size_t)4*1024*1024);
    float*  zbuf = (float*)(ws + (size_t)12*1024*1024);
    double* dsum = (double*)(ws + 14680064);
    double *s0 = dsum, *sq0 = dsum + 64, *s1 = dsum + 128, *sq1 = dsum + 192;
    float* coef  = (float*)(ws + 14682112);
    float *a0 = coef, *c0 = coef + 64, *a1 = coef + 128, *c1 = coef + 192;
    size_t base2 = 14688256;
    float4* pos4s = (float4*)(ws + base2);                   // 1 MB
    int* counts   = (int*)(ws + base2 + (1u<<20));           // 32 KB
    int* cursors  = counts + B_*NBK;                         // 32 KB
    int* off      = cursors + B_*NBK;                        // 8*1025*4
    int* xminI    = off + B_*(NBK+1);                        // 32 KB
    int* xmaxI    = xminI + B_*NBK;                          // 32 KB
    float* xlub   = (float*)(xmaxI + B_*NBK);                // 32 KB
    float* xglb   = xlub + B_*NBK;                           // 32 KB

    float* xout = (float*)d_out;
    float* vout = xout + (size_t)N_ * 64;

    hipMemsetAsync(dsum, 0, 2048, stream);
    init_bins<<<B_*NBK/256, 256, 0, stream>>>(counts, cursors, xminI, xmaxI);
    count_kernel<<<N_/256, 256, 0, stream>>>(vc, counts, xminI, xmaxI);
    scan_kernel<<<B_, NBK, 0, stream>>>(counts, xminI, xmaxI, off, xlub, xglb);
    scatter_kernel<<<N_/256, 256, 0, stream>>>(vc, off, cursors, pos4s);
    knn3_kernel<<<N_/64, 256, 0, stream>>>(pos4s, xlub, xglb, idx, scal);

    // ---- layer 1 (CIN=4: direct path; z-factoring not profitable) ----
    edge_kernel<4,32,true ,false><<<1024, 256, 0, stream>>>(pillar, idx, scal, W0, b0, wk0, wq0,
                                                            nullptr, nullptr, s0, sq0, nullptr,
                                                            nullptr, 0, 8);
    finalize_kernel<<<1, 64, 0, stream>>>(s0, sq0, g0, be0, a0, c0, 32);
    edge_kernel<4,32,false,false><<<1024, 256, 0, stream>>>(pillar, idx, scal, W0, b0, wk0, wq0,
                                                            a0, c0, nullptr, nullptr, x1,
                                                            nullptr, 0, 8);

    // ---- layer 2 (z-factored, per-batch; z table 2 MB = L2-resident) ----
    for (int b = 0; b < B_; ++b) {
        zgemm_kernel<<<512, 256, 0, stream>>>(x1, W1, zbuf, b);
        edge_kernel<32,64,true ,true><<<2048, 256, 0, stream>>>(x1, idx, scal, W1, b1, wk1, wq1,
                                                                nullptr, nullptr, s1, sq1, nullptr,
                                                                zbuf, b, 1);
    }
    finalize_kernel<<<1, 64, 0, stream>>>(s1, sq1, g1, be1, a1, c1, 64);
    for (int b = 0; b < B_; ++b) {
        zgemm_kernel<<<512, 256, 0, stream>>>(x1, W1, zbuf, b);
        edge_kernel<32,64,false,true><<<2048, 256, 0, stream>>>(x1, idx, scal, W1, b1, wk1, wq1,
                                                                a1, c1, nullptr, nullptr, xout,
                                                                zbuf, b, 1);
    }

    copy_vc<<<256, 256, 0, stream>>>((const float4*)vc, (float4*)vout);
}

// Round 4
// 552.759 us; speedup vs baseline: 2.2290x; 2.2290x over previous
//
#include <hip/hip_runtime.h>
#include <hip/hip_fp16.h>
#include <math.h>

#define B_ 8
#define P_ 8192
#define N_ 65536
#define K_ 16
#define EPS_ 1e-5f
#define NBK 1024                 // x-buckets per batch
#define BSCALE 20.48f            // NBK / 50.0

// ============================ binning (R5, proven) =========================
__global__ __launch_bounds__(256) void init_bins(int* counts, int* cursors,
                                                 int* xminI, int* xmaxI) {
    int i = blockIdx.x * 256 + threadIdx.x;   // 8192 entries
    counts[i] = 0; cursors[i] = 0;
    xminI[i] = 0x7F7FFFFF;                    // non-neg floats: int order == float order
    xmaxI[i] = 0x80000000;
}

__device__ __forceinline__ int bucket_of(float x) {
    int b = (int)(x * BSCALE);
    return b > (NBK - 1) ? (NBK - 1) : (b < 0 ? 0 : b);
}

__global__ __launch_bounds__(256) void count_kernel(const float* __restrict__ vc,
                                                    int* counts, int* xminI, int* xmaxI) {
    int q = blockIdx.x * 256 + threadIdx.x;
    float4 p = ((const float4*)vc)[q];        // [batch, x, y, z]
    int b = q >> 13;
    int bk = bucket_of(p.y);
    int e = b * NBK + bk;
    atomicAdd(&counts[e], 1);
    int xb = __float_as_int(p.y);
    atomicMin(&xminI[e], xb);
    atomicMax(&xmaxI[e], xb);
}

__global__ __launch_bounds__(1024) void scan_kernel(const int* __restrict__ counts,
                                                    const int* __restrict__ xminI,
                                                    const int* __restrict__ xmaxI,
                                                    int* off, float* xlub, float* xglb) {
    __shared__ int   smi[NBK];
    __shared__ float smf[NBK];
    int b = blockIdx.x, t = threadIdx.x;
    int e = b * NBK + t;

    int c = counts[e];
    smi[t] = c; __syncthreads();
    for (int s = 1; s < NBK; s <<= 1) {
        int u = smi[t]; int v = (t >= s) ? smi[t - s] : 0;
        __syncthreads(); smi[t] = u + v; __syncthreads();
    }
    off[b * (NBK + 1) + t] = smi[t] - c;
    if (t == NBK - 1) off[b * (NBK + 1) + NBK] = smi[t];

    float mx = c ? __int_as_float(xmaxI[e]) : -1e30f;
    smf[t] = mx; __syncthreads();
    for (int s = 1; s < NBK; s <<= 1) {
        float u = smf[t]; float v = (t >= s) ? smf[t - s] : -1e30f;
        __syncthreads(); smf[t] = fmaxf(u, v); __syncthreads();
    }
    xlub[e] = smf[t];
    __syncthreads();

    int r = NBK - 1 - t;
    int cr_ = counts[b * NBK + r];
    float mn = cr_ ? __int_as_float(xminI[b * NBK + r]) : 1e30f;
    smf[t] = mn; __syncthreads();
    for (int s = 1; s < NBK; s <<= 1) {
        float u = smf[t]; float v = (t >= s) ? smf[t - s] : 1e30f;
        __syncthreads(); smf[t] = fminf(u, v); __syncthreads();
    }
    xglb[b * NBK + r] = smf[t];
}

__global__ __launch_bounds__(256) void scatter_kernel(const float* __restrict__ vc,
                                                      const int* __restrict__ off,
                                                      int* cursors, float4* pos4s) {
    int q = blockIdx.x * 256 + threadIdx.x;
    float4 p = ((const float4*)vc)[q];
    int b = q >> 13;
    int bk = bucket_of(p.y);
    int slot = off[b * (NBK + 1) + bk] + atomicAdd(&cursors[b * NBK + bk], 1);
    pos4s[(b << 13) + slot] = make_float4(p.y, p.z, p.w, __int_as_float(q));
}

// ============== knn: single-pass exact top-k, packed f64 keys ==============
// (R2, proven 187 us.) Epilogue computes scal = 2*sigmoid(-sqrt(d2)) once
// and stores f16 (removes sqrt/exp from both edge layers).
__global__ __launch_bounds__(256, 4) void knn3_kernel(const float4* __restrict__ pos4s,
                                                   const float* __restrict__ xlub,
                                                   const float* __restrict__ xglb,
                                                   unsigned short* __restrict__ idx_out,
                                                   __half* __restrict__ scal_out) {
    const int tid   = threadIdx.x;
    const int sub   = tid & 3;                     // position within quad
    const int bb    = blockIdx.x >> 7;             // batch (128 blocks/batch)
    const int bbase = bb << 13;
    const int wq    = blockIdx.x & 127;            // 64-query group within batch
    const int home0 = bbase + ((wq >> 2) << 8);    // aligned 256-tile containing group
    const int qslot = bbase + (wq << 6) + (tid >> 2);
    const float4 me = pos4s[qslot];
    const float qx = me.x, qy = me.y, qz = me.z;
    const int q = __float_as_int(me.w);
    const float* xl = xlub + (bb << 10);
    const float* xg = xglb + (bb << 10);

    __shared__ __align__(16) float4 tile[256];       // 4 KB
    __shared__ int sflags[2];

    const double KINF = __longlong_as_double(0x7F800000LL << 16);  // (inf, idx 0)
    double bd[16];
#pragma unroll
    for (int t = 0; t < 16; ++t) bd[t] = KINF;
    float bd15f = __builtin_huge_valf();             // own 16th distance
    float sbdf  = __builtin_huge_valf();             // quad-union 16th distance

    // 4-stage bitonic cleanup: sorts the bitonic lower-half of a merge.
    auto CLEAN16 = [](double* m) {
#pragma unroll
        for (int dd = 8; dd >= 1; dd >>= 1)
#pragma unroll
            for (int i = 0; i < 16; ++i)
                if ((i & dd) == 0) {
                    double lo = fmin(m[i], m[i | dd]);
                    m[i | dd] = fmax(m[i], m[i | dd]);
                    m[i] = lo;
                }
    };

    // exact union-16th KEY across the quad (all 4 lanes compute same value)
    auto QUAD16K = [&]() -> double {
        double m[16];
#pragma unroll
        for (int i = 0; i < 16; ++i)
            m[i] = fmin(bd[i], __shfl_xor(bd[15 - i], 1, 64));
        CLEAN16(m);
        double t = 0.0;
#pragma unroll
        for (int i = 0; i < 16; ++i)
            t = fmax(t, fmin(m[i], __shfl_xor(m[15 - i], 2, 64)));
        return t;
    };

#define DIST_(c)                                                            \
    float dx = __fsub_rn(qx, (c).x);                                        \
    float dy = __fsub_rn(qy, (c).y);                                        \
    float dz = __fsub_rn(qz, (c).z);                                        \
    float d  = __fadd_rn(__fadd_rn(__fmul_rn(dx,dx), __fmul_rn(dy,dy)),     \
                         __fmul_rn(dz,dz));

#define SCAN_(base, cntT) {                                                 \
    __syncthreads();                                                        \
    if (tid < (cntT)) tile[tid] = pos4s[(base) + tid];                      \
    __syncthreads();                                                        \
    float g_ = fminf(bd15f, sbdf);                                          \
    _Pragma("unroll 4")                                                     \
    for (int j = sub; j < (cntT); j += 4) {                                 \
        float4 c = tile[j];                                                 \
        DIST_(c)                                                            \
        if (d <= g_) {                                                      \
            double key = __longlong_as_double(                              \
                ((long long)((unsigned long long)__float_as_uint(d) << 16)) \
                | (long long)(unsigned long long)((unsigned)__float_as_int(c.w) & 0xFFFFu)); \
            _Pragma("unroll")                                               \
            for (int t = 15; t > 0; --t)                                    \
                bd[t] = fmin(bd[t], fmax(bd[t-1], key));                    \
            bd[0] = fmin(bd[0], key);                                       \
            bd15f = __uint_as_float((unsigned)                              \
                ((unsigned long long)__double_as_longlong(bd[15]) >> 16));  \
            g_ = fminf(bd15f, sbdf);                                        \
        }                                                                   \
    } }

    // ---- home tile, then center-outward expansion (single pass) ----
    SCAN_(home0, 256)
    int sL = home0, sR = home0 + 256;
    for (;;) {
        double sk = QUAD16K();                        // exact union 16th key
        sbdf = __uint_as_float((unsigned)
            ((unsigned long long)__double_as_longlong(sk) >> 16));
        bool needL = false, needR = false;
        if (sL > bbase) {
            float xb = xl[bucket_of(pos4s[sL - 1].x)];   // ub on x of slots < sL
            float t = __fsub_rn(qx, xb);
            needL = __fmul_rn(t, t) <= sbdf;             // tie-inclusive
        }
        if (sR < bbase + P_) {
            float xb = xg[bucket_of(pos4s[sR].x)];       // lb on x of slots >= sR
            float t = __fsub_rn(xb, qx);
            needR = __fmul_rn(t, t) <= sbdf;
        }
        if (tid == 0) { sflags[0] = 0; sflags[1] = 0; }
        __syncthreads();
        if (needL) sflags[0] = 1;
        if (needR) sflags[1] = 1;
        __syncthreads();
        int aL = sflags[0], aR = sflags[1];
        if (!aL && !aR) break;
        if (aL) { int c_ = min(256, sL - bbase);       SCAN_(sL - c_, c_) sL -= c_; }
        if (aR) { int c_ = min(256, bbase + P_ - sR);  SCAN_(sR, c_)      sR += c_; }
    }

    // ---- full sorted union top-16 (all 4 quad lanes converge) ----
    double m[16];
#pragma unroll
    for (int i = 0; i < 16; ++i)
        m[i] = fmin(bd[i], __shfl_xor(bd[15 - i], 1, 64));
    CLEAN16(m);
    double u[16];
#pragma unroll
    for (int i = 0; i < 16; ++i)
        u[i] = fmin(m[i], __shfl_xor(m[15 - i], 2, 64));
    CLEAN16(u);

    // lane sub==0 writes: idx (sorted ascending by (d,idx), exact lax.top_k
    // order) and the f16 precomputed scale.
    if (sub == 0) {
        unsigned long long kk[16];
#pragma unroll
        for (int t = 0; t < 16; ++t)
            kk[t] = (unsigned long long)__double_as_longlong(u[t]);

        ushort4* i4 = (ushort4*)(idx_out + (size_t)q * K_);
        i4[0] = make_ushort4((unsigned short)(kk[0] & 0xFFFFu), (unsigned short)(kk[1] & 0xFFFFu),
                             (unsigned short)(kk[2] & 0xFFFFu), (unsigned short)(kk[3] & 0xFFFFu));
        i4[1] = make_ushort4((unsigned short)(kk[4] & 0xFFFFu), (unsigned short)(kk[5] & 0xFFFFu),
                             (unsigned short)(kk[6] & 0xFFFFu), (unsigned short)(kk[7] & 0xFFFFu));
        i4[2] = make_ushort4((unsigned short)(kk[8] & 0xFFFFu), (unsigned short)(kk[9] & 0xFFFFu),
                             (unsigned short)(kk[10] & 0xFFFFu), (unsigned short)(kk[11] & 0xFFFFu));
        i4[3] = make_ushort4((unsigned short)(kk[12] & 0xFFFFu), (unsigned short)(kk[13] & 0xFFFFu),
                             (unsigned short)(kk[14] & 0xFFFFu), (unsigned short)(kk[15] & 0xFFFFu));

        unsigned pw[8];
#pragma unroll
        for (int i = 0; i < 8; ++i) {
            float d0 = __uint_as_float((unsigned)(kk[2*i]     >> 16));
            float d1 = __uint_as_float((unsigned)(kk[2*i + 1] >> 16));
            float e0 = __expf(-sqrtf(d0));
            float e1 = __expf(-sqrtf(d1));
            float s0 = 2.0f * e0 / (1.0f + e0);
            float s1 = 2.0f * e1 / (1.0f + e1);
            pw[i] = (unsigned)__half_as_ushort(__float2half_rn(s0))
                  | ((unsigned)__half_as_ushort(__float2half_rn(s1)) << 16);
        }
        uint4* s4 = (uint4*)(scal_out + (size_t)q * K_);
        s4[0] = make_uint4(pw[0], pw[1], pw[2], pw[3]);
        s4[1] = make_uint4(pw[4], pw[5], pw[6], pw[7]);
    }
#undef SCAN_
#undef DIST_
}

// ================= zgemm_all: full-N neighbor projection ===================
// z[m][o] = sum_c Wr1[o][c] * x1[m][c]   (Wr1 = W1[:, 32:64])
// x1 rows live STRIDED in d_out (row m at xout + m*64 floats, first 32 used).
// ONE launch for all N (R3's per-batch serialization was the regression).
// Output z f16: 8 MB table; per-batch slice 1 MB -> L2-resident for gathers.
__global__ __launch_bounds__(256) void zgemm_all(const float* __restrict__ x1,
                                                 const float* __restrict__ W,  // 64 x 64
                                                 __half* __restrict__ z) {
    const int o  = threadIdx.x & 63;
    const int pg = threadIdx.x >> 6;
    float Wr[32];
    const float4* w4 = (const float4*)(W + o * 64 + 32);
#pragma unroll
    for (int c = 0; c < 8; ++c) {
        float4 v = w4[c];
        Wr[4*c] = v.x; Wr[4*c+1] = v.y; Wr[4*c+2] = v.z; Wr[4*c+3] = v.w;
    }
    const int m0 = blockIdx.x * 16 + pg * 4;
#pragma unroll
    for (int i = 0; i < 4; ++i) {
        const int m = m0 + i;
        const float4* xr = (const float4*)x1 + (size_t)m * 16;   // stride 64 floats
        float acc = 0.f;
#pragma unroll
        for (int c = 0; c < 8; ++c) {
            float4 v = xr[c];
            acc = fmaf(Wr[4*c  ], v.x, acc);
            acc = fmaf(Wr[4*c+1], v.y, acc);
            acc = fmaf(Wr[4*c+2], v.z, acc);
            acc = fmaf(Wr[4*c+3], v.w, acc);
        }
        z[((size_t)m << 6) + o] = __float2half_rn(acc);
    }
}

// ============================ edgeconv (barrier-free) ======================
// Wave-internal groups (R1/R2, proven). USEZ (layer 2, R4 single-launch):
// h = relu(u + z[idx[k]][o]) with u = Ad.xi + b (32 fma once per point) and
// z gathered from the full-N f16 table (lane o reads z[j*64+o] -> 128 B
// coalesced, L2-resident). No LDS staging, no per-edge GEMM, no Wr regs.
// Phases A and B use the identical u+z path -> BN statistics match the data
// path exactly. xs4 = x row stride in float4 units (L1: 1; L2: 16, rows
// strided inside d_out). ostr = out row stride in floats (64 both layers).
template<int CIN, int COUT, bool PHA, bool USEZ>
__global__ __launch_bounds__(256) void edge_kernel(
    const float* __restrict__ x,
    const unsigned short* __restrict__ idx,
    const __half* __restrict__ scal,
    const float* __restrict__ W,
    const float* __restrict__ bias,
    const float* __restrict__ wk,
    const float* __restrict__ wq,
    const float* __restrict__ acoef,
    const float* __restrict__ ccoef,
    double* __restrict__ gsum,
    double* __restrict__ gsumsq,
    float* __restrict__ out,
    const __half* __restrict__ zbuf,
    int xs4, int ostr, int niter)
{
    constexpr int LOGC = (COUT == 64) ? 6 : 5;
    constexpr int GPW  = 64 / COUT;
    constexpr int GPB  = 4 * GPW;
    constexpr int C4   = CIN / 4;
    constexpr int SJ   = USEZ ? 4 : ((K_ + 1) * CIN);
    constexpr int HTS  = COUT + 1;
    constexpr int HTN  = PHA ? 1 : (K_ * HTS);
    constexpr int PN   = PHA ? 1 : (K_ * K_);
    constexpr int KQN  = PHA ? 1 : (2 * K_);
    constexpr int SCN  = PHA ? 1 : K_;
    constexpr int WKQN = PHA ? 1 : (2 * COUT);

    const int tid  = threadIdx.x;
    const int wave = tid >> 6;
    const int lane = tid & 63;
    const int lo   = lane & (COUT - 1);
    const int grp  = lane >> LOGC;
    const int gidx = wave * GPW + grp;

    __shared__ __align__(16) float sj_s[GPB][SJ];
    __shared__ __align__(16) float hT_s[GPB][HTN];
    __shared__ __align__(16) float p_s[GPB][PN];
    __shared__ __align__(16) float kqv_s[GPB][KQN];
    __shared__ __align__(16) float rden_s[GPB][SCN];
    __shared__ __align__(16) float scal_s[GPB][SCN];
    __shared__ __align__(16) float wkq_s[WKQN];

    float Ad[CIN];
    float Wr[USEZ ? 1 : CIN];
#pragma unroll
    for (int c = 0; c < CIN; ++c) {
        float wl = W[lo * (2*CIN) + c];
        float wr = W[lo * (2*CIN) + CIN + c];
        Ad[c] = wl - wr;
        if constexpr (!USEZ) Wr[c] = wr;
    }
    const float b_s = bias[lo];

    float a_s = 0.f, c_s = 0.f;
    if constexpr (!PHA) {
        a_s = acoef[lo]; c_s = ccoef[lo];
        if (tid < COUT)            wkq_s[tid] = wk[tid];
        else if (tid < 2*COUT)     wkq_s[tid] = wq[tid - COUT];
        __syncthreads();   // the ONLY block barrier (wkq_s is cross-wave)
    }

    double lsum = 0.0, lsq = 0.0;
    const int g0      = blockIdx.x * GPB + gidx;
    const int gstride = gridDim.x * GPB;

    for (int it = 0; it < niter; ++it) {
        const int n = g0 + it * gstride;

        float hn[K_];
        float psum = 0.f, psq = 0.f;

        if constexpr (USEZ) {
            // ---- u = b + Ad.x[n] (point's own row, broadcast reads) ----
            float uacc = b_s;
            const float4* xr = (const float4*)x + (size_t)n * xs4;
#pragma unroll
            for (int c = 0; c < C4; ++c) {
                float4 v = xr[c];
                uacc = fmaf(Ad[4*c  ], v.x, uacc);
                uacc = fmaf(Ad[4*c+1], v.y, uacc);
                uacc = fmaf(Ad[4*c+2], v.z, uacc);
                uacc = fmaf(Ad[4*c+3], v.w, uacc);
            }
            // ---- gather z rows (coalesced 128 B per k, L2-resident) ----
            const uint4* iw = (const uint4*)(idx + (size_t)n * K_);
            const uint4 ia = iw[0], ib = iw[1];
            float zk[K_];
#define GA(k, w, s) { unsigned j = ((w) >> (s)) & 0xFFFFu;                  \
                      zk[k] = __half2float(zbuf[((size_t)j << 6) + lo]); }
            GA(0,  ia.x, 0) GA(1,  ia.x, 16) GA(2,  ia.y, 0) GA(3,  ia.y, 16)
            GA(4,  ia.z, 0) GA(5,  ia.z, 16) GA(6,  ia.w, 0) GA(7,  ia.w, 16)
            GA(8,  ib.x, 0) GA(9,  ib.x, 16) GA(10, ib.y, 0) GA(11, ib.y, 16)
            GA(12, ib.z, 0) GA(13, ib.z, 16) GA(14, ib.w, 0) GA(15, ib.w, 16)
#undef GA
#pragma unroll
            for (int k = 0; k < K_; ++k) {
                float h = fmaxf(uacc + zk[k], 0.f);
                if constexpr (PHA) { psum += h; psq = fmaf(h, h, psq); }
                else               hn[k] = fmaf(a_s, h, c_s);
            }
            if constexpr (!PHA) {
                if (lo < K_)
                    scal_s[gidx][lo] = __half2float(scal[(size_t)n * K_ + lo]);
            }
            __builtin_amdgcn_wave_barrier();   // scal_s -> epilogue reads
        } else {
            // ---- stage xj rows (k<K) and xi row (k==K) into LDS (float4) ----
            {
                const float4* xs  = (const float4*)x;
                float4*       sj4 = (float4*)sj_s[gidx];
                constexpr int TOT4 = (K_ + 1) * C4;
#pragma unroll
                for (int e0 = 0; e0 < TOT4; e0 += COUT) {
                    int e = e0 + lo;
                    if (e < TOT4) {
                        int r = e / C4;
                        int c = e - r * C4;
                        int row = (r < K_) ? (int)idx[n * K_ + r] : n;
                        sj4[e] = xs[row * xs4 + c];
                    }
                }
            }
            if constexpr (!PHA) {
                if (lo < K_)
                    scal_s[gidx][lo] = __half2float(scal[(size_t)n * K_ + lo]);
            }
            __builtin_amdgcn_wave_barrier();   // staging -> compute (wave-internal)

            const float* sj = sj_s[gidx];
            float t0 = b_s;
#pragma unroll
            for (int c = 0; c < C4; ++c) {
                float4 v = ((const float4*)(sj + K_ * CIN))[c];
                t0 = fmaf(Ad[4*c  ], v.x, t0);
                t0 = fmaf(Ad[4*c+1], v.y, t0);
                t0 = fmaf(Ad[4*c+2], v.z, t0);
                t0 = fmaf(Ad[4*c+3], v.w, t0);
            }
#pragma unroll
            for (int k = 0; k < K_; ++k) {
                float acc = t0;
                const float4* xrr = (const float4*)(sj + k * CIN);
#pragma unroll
                for (int c = 0; c < C4; ++c) {
                    float4 v = xrr[c];
                    acc = fmaf(Wr[4*c  ], v.x, acc);
                    acc = fmaf(Wr[4*c+1], v.y, acc);
                    acc = fmaf(Wr[4*c+2], v.z, acc);
                    acc = fmaf(Wr[4*c+3], v.w, acc);
                }
                float h = fmaxf(acc, 0.f);
                if constexpr (PHA) { psum += h; psq = fmaf(h, h, psq); }
                else               hn[k] = fmaf(a_s, h, c_s);
            }
        }

        if constexpr (PHA) {
            lsum += (double)psum;        // f64 only across points
            lsq  += (double)psq;
        }

        if constexpr (!PHA) {
            // transpose to LDS (padded stride -> conflict-free columns)
            float* hT = hT_s[gidx];
#pragma unroll
            for (int k = 0; k < K_; ++k) hT[k * HTS + lo] = hn[k];
            __builtin_amdgcn_wave_barrier();   // transpose -> Kv/Qv

            const int kk   = lo & 15;
            const int role = lo >> 4;
            float av = 0.f;
            const float* hrow = hT + kk * HTS;
            int obase; const float* wv;
            if constexpr (COUT == 64) { obase = (role & 1) * 32; wv = wkq_s + ((role >> 1) ? COUT : 0); }
            else                      { obase = 0;               wv = wkq_s + (role ? COUT : 0); }
#pragma unroll
            for (int j = 0; j < 32; ++j)
                av = fmaf(hrow[obase + j], wv[obase + j], av);
            if constexpr (COUT == 64) {
                // halves combine in-register: lanes {kk,kk+16}->Kv, {kk+32,kk+48}->Qv
                float sum2 = av + __shfl_xor(av, 16, 64);
                if (lo < 16)                  kqv_s[gidx][kk] = sum2;        // Kv
                else if (lo >= 32 && lo < 48) kqv_s[gidx][16 + kk] = sum2;   // Qv
            } else {
                kqv_s[gidx][lo] = av;   // [0,16)=Kv, [16,32)=Qv
            }
            __builtin_amdgcn_wave_barrier();   // kqv -> softmax

            if (lo < K_) {
                const int qq = lo;
                const float qv = kqv_s[gidx][K_ + qq];
                float mx = -__builtin_huge_valf();
#pragma unroll
                for (int k = 0; k < K_; ++k) mx = fmaxf(mx, kqv_s[gidx][k] * qv);
                float den = 0.f;
#pragma unroll
                for (int k = 0; k < K_; ++k) {
                    float e = __expf(kqv_s[gidx][k] * qv - mx);
                    den += e;
                    p_s[gidx][k * K_ + qq] = e;
                }
                rden_s[gidx][qq] = 1.0f / den;
            }
            __builtin_amdgcn_wave_barrier();   // softmax -> weighted sum

            float hq[K_];
#pragma unroll
            for (int qq = 0; qq < K_; ++qq) hq[qq] = 0.f;
#pragma unroll
            for (int k = 0; k < K_; ++k) {
                const float hnk = hn[k];
                const float4* p4 = (const float4*)(p_s[gidx] + k * K_);
#pragma unroll
                for (int j = 0; j < 4; ++j) {
                    float4 v = p4[j];
                    hq[4*j  ] = fmaf(hnk, v.x, hq[4*j  ]);
                    hq[4*j+1] = fmaf(hnk, v.y, hq[4*j+1]);
                    hq[4*j+2] = fmaf(hnk, v.z, hq[4*j+2]);
                    hq[4*j+3] = fmaf(hnk, v.w, hq[4*j+3]);
                }
            }
            float res = -__builtin_huge_valf();
#pragma unroll
            for (int j = 0; j < 4; ++j) {
                float4 sc = ((const float4*)scal_s[gidx])[j];
                float4 rd = ((const float4*)rden_s[gidx])[j];
                res = fmaxf(res, sc.x * (hq[4*j  ] * rd.x));
                res = fmaxf(res, sc.y * (hq[4*j+1] * rd.y));
                res = fmaxf(res, sc.z * (hq[4*j+2] * rd.z));
                res = fmaxf(res, sc.w * (hq[4*j+3] * rd.w));
            }
            out[(size_t)n * ostr + lo] = res;
            __builtin_amdgcn_wave_barrier();   // epilogue -> next-iter staging
        } else {
            __builtin_amdgcn_wave_barrier();   // compute -> next-iter staging
        }
    }

    if constexpr (PHA) {
        if constexpr (COUT == 32) {
            // fold the two half-wave groups (shuffle across lane 32 boundary)
            long long bs = __double_as_longlong(lsum);
            int l0 = __shfl_xor((int)(bs & 0xffffffffLL), 32, 64);
            int h0 = __shfl_xor((int)(bs >> 32), 32, 64);
            lsum += __longlong_as_double(((long long)h0 << 32) | (unsigned long long)(unsigned int)l0);
            bs = __double_as_longlong(lsq);
            l0 = __shfl_xor((int)(bs & 0xffffffffLL), 32, 64);
            h0 = __shfl_xor((int)(bs >> 32), 32, 64);
            lsq += __longlong_as_double(((long long)h0 << 32) | (unsigned long long)(unsigned int)l0);
        }
        __shared__ double redS[4][COUT];
        __shared__ double redQ[4][COUT];
        if (lane < COUT) { redS[wave][lane] = lsum; redQ[wave][lane] = lsq; }
        __syncthreads();
        if (tid < COUT) {
            double ss = redS[0][tid] + redS[1][tid] + redS[2][tid] + redS[3][tid];
            double qq = redQ[0][tid] + redQ[1][tid] + redQ[2][tid] + redQ[3][tid];
            atomicAdd(&gsum[tid], ss);
            atomicAdd(&gsumsq[tid], qq);
        }
    }
}

__global__ void finalize_kernel(const double* __restrict__ gsum, const double* __restrict__ gsumsq,
                                const float* __restrict__ gamma, const float* __restrict__ beta,
                                float* __restrict__ a, float* __restrict__ c, int cout)
{
    int o = threadIdx.x;
    if (o < cout) {
        const double inv = 1.0 / ((double)N_ * (double)K_);
        double mu  = gsum[o] * inv;
        double var = gsumsq[o] * inv - mu * mu;
        double rs  = 1.0 / sqrt(var + (double)EPS_);
        double av  = rs * (double)gamma[o];
        a[o] = (float)av;
        c[o] = (float)((double)beta[o] - mu * av);
    }
}

__global__ __launch_bounds__(256) void copy_vc(const float4* __restrict__ src,
                                               float4* __restrict__ dst) {
    int i = blockIdx.x * 256 + threadIdx.x;
    dst[i] = src[i];
}

extern "C" void kernel_launch(void* const* d_in, const int* in_sizes, int n_in,
                              void* d_out, int out_size, void* d_ws, size_t ws_size,
                              hipStream_t stream)
{
    const float* pillar = (const float*)d_in[0];
    const float* vc     = (const float*)d_in[1];
    const float* W0  = (const float*)d_in[2];
    const float* b0  = (const float*)d_in[3];
    const float* g0  = (const float*)d_in[4];
    const float* be0 = (const float*)d_in[5];
    const float* wk0 = (const float*)d_in[6];
    const float* wq0 = (const float*)d_in[7];
    const float* W1  = (const float*)d_in[8];
    const float* b1  = (const float*)d_in[9];
    const float* g1  = (const float*)d_in[10];
    const float* be1 = (const float*)d_in[11];
    const float* wk1 = (const float*)d_in[12];
    const float* wq1 = (const float*)d_in[13];

    // ---- workspace map (max used ~14.68 MB, under proven 15.93 MB) ----
    // [0,2M)    idx u16  (N*K)
    // [2M,4M)   scal f16 (N*K)
    // [4M,12M)  z f16    (N*64)  -- written after knn
    // [12M,~13.28M) binning block (pos4s etc., dead after knn)
    // [14,680,064) dsum 2KB; [14,682,112) coef 1KB
    // x1 is NOT in ws: L1-B writes rows strided into d_out (row n = first
    // 128 B of xout row n). Safe: xout rows are only overwritten by L2-B
    // AFTER the owning group has read its own x1 row (same iteration,
    // program order); no cross-group reads of x1 in L2-B.
    char* ws = (char*)d_ws;
    unsigned short* idx = (unsigned short*)ws;
    __half* scal = (__half*)(ws + (size_t)2*1024*1024);
    __half* zh   = (__half*)(ws + (size_t)4*1024*1024);
    double* dsum = (double*)(ws + 14680064);
    double *s0 = dsum, *sq0 = dsum + 64, *s1 = dsum + 128, *sq1 = dsum + 192;
    float* coef  = (float*)(ws + 14682112);
    float *a0 = coef, *c0 = coef + 64, *a1 = coef + 128, *c1 = coef + 192;
    size_t base2 = (size_t)12*1024*1024;
    float4* pos4s = (float4*)(ws + base2);                   // 1 MB
    int* counts   = (int*)(ws + base2 + (1u<<20));           // 32 KB
    int* cursors  = counts + B_*NBK;                         // 32 KB
    int* off      = cursors + B_*NBK;                        // 8*1025*4
    int* xminI    = off + B_*(NBK+1);                        // 32 KB
    int* xmaxI    = xminI + B_*NBK;                          // 32 KB
    float* xlub   = (float*)(xmaxI + B_*NBK);                // 32 KB
    float* xglb   = xlub + B_*NBK;                           // 32 KB

    float* xout = (float*)d_out;
    float* vout = xout + (size_t)N_ * 64;

    hipMemsetAsync(dsum, 0, 2048, stream);
    init_bins<<<B_*NBK/256, 256, 0, stream>>>(counts, cursors, xminI, xmaxI);
    count_kernel<<<N_/256, 256, 0, stream>>>(vc, counts, xminI, xmaxI);
    scan_kernel<<<B_, NBK, 0, stream>>>(counts, xminI, xmaxI, off, xlub, xglb);
    scatter_kernel<<<N_/256, 256, 0, stream>>>(vc, off, cursors, pos4s);
    knn3_kernel<<<N_/64, 256, 0, stream>>>(pos4s, xlub, xglb, idx, scal);

    // ---- layer 1 (CIN=4: direct LDS-staged path) ----
    edge_kernel<4,32,true ,false><<<1024, 256, 0, stream>>>(pillar, idx, scal, W0, b0, wk0, wq0,
                                                            nullptr, nullptr, s0, sq0, nullptr,
                                                            nullptr, 1, 0, 8);
    finalize_kernel<<<1, 64, 0, stream>>>(s0, sq0, g0, be0, a0, c0, 32);
    edge_kernel<4,32,false,false><<<1024, 256, 0, stream>>>(pillar, idx, scal, W0, b0, wk0, wq0,
                                                            a0, c0, nullptr, nullptr, xout,
                                                            nullptr, 1, 64, 8);

    // ---- layer 2: one zgemm for all N, then single-launch edges ----
    zgemm_all<<<N_/16, 256, 0, stream>>>(xout, W1, zh);
    edge_kernel<32,64,true ,true><<<2048, 256, 0, stream>>>(xout, idx, scal, W1, b1, wk1, wq1,
                                                            nullptr, nullptr, s1, sq1, nullptr,
                                                            zh, 16, 0, 8);
    finalize_kernel<<<1, 64, 0, stream>>>(s1, sq1, g1, be1, a1, c1, 64);
    edge_kernel<32,64,false,true><<<2048, 256, 0, stream>>>(xout, idx, scal, W1, b1, wk1, wq1,
                                                            a1, c1, nullptr, nullptr, xout,
                                                            zh, 16, 64, 8);

    copy_vc<<<256, 256, 0, stream>>>((const float4*)vc, (float4*)vout);
}